// Round 6
// baseline (348.879 us; speedup 1.0000x reference)
//
#include <hip/hip_runtime.h>
#include <math.h>

#define NB 16
#define NH 512
#define NW 512
#define NHW (NH * NW)
#define LAM2 0.01f
#define TOLV 0.001f
#define MAXIT 10
#define ROWS 8                  // rows per block strip
#define NCHUNK (NH / ROWS)      // 64 strips per batch
#define NTHREADS 256
#define COMP_STRIDE (NB * NCHUNK)

// ws layout:
//   [0 .. 5*NB*NCHUNK) doubles : partial sums, layout [comp][b][strip]
//   PWS_OFF : 32 floats : current p
//   ERR_OFF : 1 float   : current err
#define PARTIALS_N (5 * NB * NCHUNK)
#define PWS_OFF (PARTIALS_N * 8)
#define ERR_OFF (PWS_OFF + 32 * 4)

__device__ __forceinline__ float cubicf(float t) {
    float a = fabsf(t);
    float a2 = a * a;
    float a3 = a2 * a;
    if (a <= 1.0f) return 1.5f * a3 - 2.5f * a2 + 1.0f;
    if (a < 2.0f)  return -0.5f * a3 + 2.5f * a2 - 4.0f * a + 2.0f;
    return 0.0f;
}

// Per-column bicubic weights + clamped tap indices, bit-identical to reference
__device__ __forceinline__ void col_setup(int c, float tx, float* wx, int* xi) {
    float gx = (float)c + tx;
    float fx = floorf(gx);
    int x0 = (int)fx;
    float dx = gx - fx;
    wx[0] = cubicf(dx + 1.0f);
    wx[1] = cubicf(dx);
    wx[2] = cubicf(dx - 1.0f);
    wx[3] = cubicf(dx - 2.0f);
#pragma unroll
    for (int i = 0; i < 4; ++i) xi[i] = min(max(x0 - 1 + i, 0), NW - 1);
}

// Horizontal bicubic for a column pair on one source row.
// fast: the 8 taps are the 5 contiguous elements row[base..base+4]
//       (exact per-thread condition checked at setup; holds for all
//        non-border lanes) -> 1 unaligned float4 + 1 scalar load.
// slow: exact clamped scalar gathers (border lanes only).
__device__ __forceinline__ void hrow2(const float* __restrict__ row,
                                      bool fast, int base,
                                      const int* xiA, const int* xiB,
                                      const float* wxA, const float* wxB,
                                      float& HA, float& HB) {
    if (fast) {
        const float4 F = *(const float4*)(row + base);
        const float e = row[base + 4];
        HA = wxA[0] * F.x + wxA[1] * F.y + wxA[2] * F.z + wxA[3] * F.w;
        HB = wxB[0] * F.y + wxB[1] * F.z + wxB[2] * F.w + wxB[3] * e;
    } else {
        HA = wxA[0] * row[xiA[0]] + wxA[1] * row[xiA[1]] +
             wxA[2] * row[xiA[2]] + wxA[3] * row[xiA[3]];
        HB = wxB[0] * row[xiB[0]] + wxB[1] * row[xiB[1]] +
             wxB[2] * row[xiB[2]] + wxB[3] * row[xiB[3]];
    }
}

__global__ __launch_bounds__(64) void gn_init(const float* __restrict__ p_in,
                                              float* __restrict__ pws,
                                              float* __restrict__ errws) {
    int t = threadIdx.x;
    if (t < 2 * NB) pws[t] = p_in[t];
    if (t == 0) errws[0] = 1e10f;
}

__global__ __launch_bounds__(NTHREADS) void gn_reduce(const float* __restrict__ I1,
                                                      const float* __restrict__ I2,
                                                      const float* __restrict__ pws,
                                                      double* __restrict__ partials) {
    const int b = blockIdx.y;
    const int strip = blockIdx.x;
    const int tid = threadIdx.x;
    const float tx = pws[2 * b];
    const float ty = pws[2 * b + 1];
    const float* I1b = I1 + (size_t)b * NHW;
    const float* I2b = I2 + (size_t)b * NHW;

    const int cA = 2 * tid;
    const int cB = 2 * tid + 1;
    float wxA[4], wxB[4];
    int xiA[4], xiB[4];
    col_setup(cA, tx, wxA, xiA);
    col_setup(cB, tx, wxB, xiB);
    const bool fast = (xiA[3] == xiA[0] + 3) &&
                      (xiB[0] == xiA[1]) && (xiB[1] == xiA[2]) &&
                      (xiB[2] == xiA[3]) && (xiB[3] == xiA[3] + 1);
    const int base = xiA[0];

    __shared__ float wyS[ROWS][4];
    __shared__ int   yjS[ROWS][4];
    __shared__ int   alignS[ROWS];

    const int y0row = strip * ROWS;
    if (tid < ROWS) {
        int y = y0row + tid;
        float gy = (float)y + ty;
        float fy = floorf(gy);
        int yy0 = (int)fy;
        float dy = gy - fy;
        wyS[tid][0] = cubicf(dy + 1.0f);
        wyS[tid][1] = cubicf(dy);
        wyS[tid][2] = cubicf(dy - 1.0f);
        wyS[tid][3] = cubicf(dy - 2.0f);
        int yj[4], yk[4];
#pragma unroll
        for (int i = 0; i < 4; ++i) yj[i] = min(max(yy0 - 1 + i, 0), NH - 1);
        // next row's taps (recomputed) for the roll-alignment flag
        float gy2 = (float)(y + 1) + ty;
        int yy1 = (int)floorf(gy2);
#pragma unroll
        for (int i = 0; i < 4; ++i) yk[i] = min(max(yy1 - 1 + i, 0), NH - 1);
#pragma unroll
        for (int i = 0; i < 4; ++i) yjS[tid][i] = yj[i];
        alignS[tid] = (yk[0] == yj[1]) && (yk[1] == yj[2]) && (yk[2] == yj[3]);
    }

    // I1 rolling rows (for gradients)
    float2 ccPrev = make_float2(0.0f, 0.0f);
    if (y0row > 0) ccPrev = *(const float2*)(I1b + (size_t)(y0row - 1) * NW + cA);
    float2 ccCur = *(const float2*)(I1b + (size_t)y0row * NW + cA);
    float2 ccNextP = *(const float2*)(I1b + (size_t)min(y0row + 1, NH - 1) * NW + cA);

    __syncthreads();   // wyS/yjS/alignS visible (only barrier before the tail)

    // H window for output row 0: rows yjS[0][0..2]
    float HA0, HA1, HA2, HB0, HB1, HB2;
    hrow2(I2b + (size_t)yjS[0][0] * NW, fast, base, xiA, xiB, wxA, wxB, HA0, HB0);
    hrow2(I2b + (size_t)yjS[0][1] * NW, fast, base, xiA, xiB, wxA, wxB, HA1, HB1);
    hrow2(I2b + (size_t)yjS[0][2] * NW, fast, base, xiA, xiB, wxA, wxB, HA2, HB2);

    double a0 = 0, a1 = 0, a2 = 0, a3 = 0, a4 = 0;

#pragma unroll
    for (int r = 0; r < ROWS; ++r) {
        const int y = y0row + r;

        // 4th tap row for this output row
        float HA3, HB3;
        hrow2(I2b + (size_t)yjS[r][3] * NW, fast, base, xiA, xiB, wxA, wxB, HA3, HB3);

        // stage next I1 row
        float2 ncc = ((const float2*)(I1b + (size_t)min(y + 2, NH - 1) * NW))[tid];

        // I1 gradients from registers + cross-lane
        float2 ccNext = ccNextP;
        const float* I1r = I1b + (size_t)y * NW;
        float left = __shfl_up(ccCur.y, 1);
        if ((tid & 63) == 0) left = (tid > 0) ? I1r[cA - 1] : 0.0f;
        float right = __shfl_down(ccCur.x, 1);
        if ((tid & 63) == 63) right = (tid < NTHREADS - 1) ? I1r[cB + 1] : 0.0f;
        float IxA = (cA >= 1) ? 0.5f * (ccCur.y - left) : 0.0f;
        float IxB = (cB <= NW - 2) ? 0.5f * (right - ccCur.x) : 0.0f;
        float IyA = 0.0f, IyB = 0.0f;
        if (y >= 1 && y <= NH - 2) {
            IyA = 0.5f * (ccNext.x - ccPrev.x);
            IyB = 0.5f * (ccNext.y - ccPrev.y);
        }

        // vertical combine (pure registers)
        const float wy0 = wyS[r][0], wy1 = wyS[r][1], wy2 = wyS[r][2], wy3 = wyS[r][3];
        float IwA = wy0 * HA0 + wy1 * HA1 + wy2 * HA2 + wy3 * HA3;
        float IwB = wy0 * HB0 + wy1 * HB1 + wy2 * HB2 + wy3 * HB3;

        float DIA = IwA - ccCur.x, DIB = IwB - ccCur.y;
        float rhoA = 1.0f / sqrtf(DIA * DIA + LAM2);
        float rhoB = 1.0f / sqrtf(DIB * DIB + LAM2);
        float drA = DIA * rhoA, drB = DIB * rhoB;

        a0 += (double)(IxA * IxA * rhoA) + (double)(IxB * IxB * rhoB);
        a1 += (double)(IxA * IyA * rhoA) + (double)(IxB * IyB * rhoB);
        a2 += (double)(IyA * IyA * rhoA) + (double)(IyB * IyB * rhoB);
        a3 += (double)(IxA * drA) + (double)(IxB * drB);
        a4 += (double)(IyA * drA) + (double)(IyB * drB);

        // roll H window
        if (r + 1 < ROWS) {
            if (alignS[r]) {
                HA0 = HA1; HA1 = HA2; HA2 = HA3;
                HB0 = HB1; HB1 = HB2; HB2 = HB3;
            } else {   // clamped border strips only
                hrow2(I2b + (size_t)yjS[r + 1][0] * NW, fast, base, xiA, xiB, wxA, wxB, HA0, HB0);
                hrow2(I2b + (size_t)yjS[r + 1][1] * NW, fast, base, xiA, xiB, wxA, wxB, HA1, HB1);
                hrow2(I2b + (size_t)yjS[r + 1][2] * NW, fast, base, xiA, xiB, wxA, wxB, HA2, HB2);
            }
        }
        ccPrev = ccCur; ccCur = ccNext; ccNextP = ncc;
    }

#pragma unroll
    for (int off = 32; off > 0; off >>= 1) {
        a0 += __shfl_down(a0, off);
        a1 += __shfl_down(a1, off);
        a2 += __shfl_down(a2, off);
        a3 += __shfl_down(a3, off);
        a4 += __shfl_down(a4, off);
    }

    __shared__ double wsum[NTHREADS / 64][5];
    int wave = tid >> 6, lane = tid & 63;
    if (lane == 0) {
        wsum[wave][0] = a0; wsum[wave][1] = a1; wsum[wave][2] = a2;
        wsum[wave][3] = a3; wsum[wave][4] = a4;
    }
    __syncthreads();
    if (tid < 5) {
        double s = wsum[0][tid] + wsum[1][tid] + wsum[2][tid] + wsum[3][tid];
        partials[(size_t)tid * COMP_STRIDE + b * NCHUNK + strip] = s;
    }
}

__global__ __launch_bounds__(128) void gn_update(const double* __restrict__ partials,
                                                 float* __restrict__ pws,
                                                 float* __restrict__ errws,
                                                 float* __restrict__ out,
                                                 int write_out) {
    __shared__ double Hs[NB][5];
    __shared__ float dpf[NB][2];
    __shared__ float pnew[2 * NB];
    const int tid = threadIdx.x;

    if (tid < NB * 5) {
        int bb = tid & 15, comp = tid >> 4;
        const double* src = partials + (size_t)comp * COMP_STRIDE + bb * NCHUNK;
        double s = 0;
#pragma unroll 8
        for (int ch = 0; ch < NCHUNK; ++ch) s += src[ch];
        Hs[bb][comp] = s;
    }
    __syncthreads();

    if (tid < NB) {
        double H00 = Hs[tid][0], H01 = Hs[tid][1], H11 = Hs[tid][2];
        double b0 = Hs[tid][3], b1 = Hs[tid][4];
        double inv = 1.0 / (H00 * H11 - H01 * H01);
        double dp0 = ( H11 * b0 - H01 * b1) * inv;
        double dp1 = (-H01 * b0 + H00 * b1) * inv;
        dpf[tid][0] = (float)dp0;
        dpf[tid][1] = (float)dp1;
    }
    __syncthreads();

    float err_old = errws[0];
    bool active = err_old > TOLV;

    if (tid < 2 * NB) {
        float pv = pws[tid];
        if (active) pv -= dpf[tid >> 1][tid & 1];
        pnew[tid] = pv;
        pws[tid] = pv;
    }

    float err_new = err_old;
    if (tid == 0) {
        if (active) {
            double n = 0;
            for (int i = 0; i < NB; ++i) {
                n += (double)dpf[i][0] * (double)dpf[i][0];
                n += (double)dpf[i][1] * (double)dpf[i][1];
            }
            err_new = (float)sqrt(n);
            errws[0] = err_new;
        }
    }
    __syncthreads();
    if (write_out) {
        if (tid < 2 * NB) out[tid] = pnew[tid];
        if (tid == 0) out[2 * NB] = err_new;
    }
}

__global__ __launch_bounds__(NTHREADS) void gn_final(const float* __restrict__ I1,
                                                     const float* __restrict__ I2,
                                                     const float* __restrict__ pws,
                                                     float* __restrict__ out) {
    const int b = blockIdx.y;
    const int strip = blockIdx.x;
    const int tid = threadIdx.x;
    const float tx = pws[2 * b];
    const float ty = pws[2 * b + 1];
    const float* I1b = I1 + (size_t)b * NHW;
    const float* I2b = I2 + (size_t)b * NHW;

    float* DIout = out + 33;
    float* IWout = out + 33 + (size_t)NB * NHW;

    const int cA = 2 * tid;
    float wxA[4], wxB[4];
    int xiA[4], xiB[4];
    col_setup(cA, tx, wxA, xiA);
    col_setup(cA + 1, tx, wxB, xiB);
    const bool fast = (xiA[3] == xiA[0] + 3) &&
                      (xiB[0] == xiA[1]) && (xiB[1] == xiA[2]) &&
                      (xiB[2] == xiA[3]) && (xiB[3] == xiA[3] + 1);
    const int base = xiA[0];

    __shared__ float wyS[ROWS][4];
    __shared__ int   yjS[ROWS][4];
    __shared__ int   alignS[ROWS];

    const int y0row = strip * ROWS;
    if (tid < ROWS) {
        int y = y0row + tid;
        float gy = (float)y + ty;
        float fy = floorf(gy);
        int yy0 = (int)fy;
        float dy = gy - fy;
        wyS[tid][0] = cubicf(dy + 1.0f);
        wyS[tid][1] = cubicf(dy);
        wyS[tid][2] = cubicf(dy - 1.0f);
        wyS[tid][3] = cubicf(dy - 2.0f);
        int yj[4], yk[4];
#pragma unroll
        for (int i = 0; i < 4; ++i) yj[i] = min(max(yy0 - 1 + i, 0), NH - 1);
        float gy2 = (float)(y + 1) + ty;
        int yy1 = (int)floorf(gy2);
#pragma unroll
        for (int i = 0; i < 4; ++i) yk[i] = min(max(yy1 - 1 + i, 0), NH - 1);
#pragma unroll
        for (int i = 0; i < 4; ++i) yjS[tid][i] = yj[i];
        alignS[tid] = (yk[0] == yj[1]) && (yk[1] == yj[2]) && (yk[2] == yj[3]);
    }

    float2 ccP = *(const float2*)(I1b + (size_t)y0row * NW + cA);
    __syncthreads();

    float HA0, HA1, HA2, HB0, HB1, HB2;
    hrow2(I2b + (size_t)yjS[0][0] * NW, fast, base, xiA, xiB, wxA, wxB, HA0, HB0);
    hrow2(I2b + (size_t)yjS[0][1] * NW, fast, base, xiA, xiB, wxA, wxB, HA1, HB1);
    hrow2(I2b + (size_t)yjS[0][2] * NW, fast, base, xiA, xiB, wxA, wxB, HA2, HB2);

#pragma unroll
    for (int r = 0; r < ROWS; ++r) {
        const int y = y0row + r;

        float HA3, HB3;
        hrow2(I2b + (size_t)yjS[r][3] * NW, fast, base, xiA, xiB, wxA, wxB, HA3, HB3);

        float2 ncc = make_float2(0.0f, 0.0f);
        if (r + 1 < ROWS)
            ncc = *(const float2*)(I1b + (size_t)(y + 1) * NW + cA);

        const float wy0 = wyS[r][0], wy1 = wyS[r][1], wy2 = wyS[r][2], wy3 = wyS[r][3];
        float IwA = wy0 * HA0 + wy1 * HA1 + wy2 * HA2 + wy3 * HA3;
        float IwB = wy0 * HB0 + wy1 * HB1 + wy2 * HB2 + wy3 * HB3;

        float2 cc = ccP;
        size_t o = (size_t)b * NHW + (size_t)y * NW + cA;
        float2 dv; dv.x = IwA - cc.x; dv.y = IwB - cc.y;
        float2 wv; wv.x = IwA; wv.y = IwB;
        *(float2*)(DIout + o) = dv;
        *(float2*)(IWout + o) = wv;

        if (r + 1 < ROWS) {
            if (alignS[r]) {
                HA0 = HA1; HA1 = HA2; HA2 = HA3;
                HB0 = HB1; HB1 = HB2; HB2 = HB3;
            } else {
                hrow2(I2b + (size_t)yjS[r + 1][0] * NW, fast, base, xiA, xiB, wxA, wxB, HA0, HB0);
                hrow2(I2b + (size_t)yjS[r + 1][1] * NW, fast, base, xiA, xiB, wxA, wxB, HA1, HB1);
                hrow2(I2b + (size_t)yjS[r + 1][2] * NW, fast, base, xiA, xiB, wxA, wxB, HA2, HB2);
            }
        }
        ccP = ncc;
    }
}

extern "C" void kernel_launch(void* const* d_in, const int* in_sizes, int n_in,
                              void* d_out, int out_size, void* d_ws, size_t ws_size,
                              hipStream_t stream) {
    const float* I1 = (const float*)d_in[0];
    const float* I2 = (const float*)d_in[1];
    const float* p  = (const float*)d_in[2];
    float* out = (float*)d_out;

    double* partials = (double*)d_ws;
    float* pws   = (float*)((char*)d_ws + PWS_OFF);
    float* errws = (float*)((char*)d_ws + ERR_OFF);

    gn_init<<<1, 64, 0, stream>>>(p, pws, errws);

    dim3 grid(NCHUNK, NB);
    for (int t = 0; t < MAXIT; ++t) {
        gn_reduce<<<grid, NTHREADS, 0, stream>>>(I1, I2, pws, partials);
        gn_update<<<1, 128, 0, stream>>>(partials, pws, errws, out, (t == MAXIT - 1) ? 1 : 0);
    }
    gn_final<<<grid, NTHREADS, 0, stream>>>(I1, I2, pws, out);
}

// Round 7
// 264.474 us; speedup vs baseline: 1.3191x; 1.3191x over previous
//
#include <hip/hip_runtime.h>
#include <math.h>

#define NB 16
#define NH 512
#define NW 512
#define NHW (NH * NW)
#define LAM2 0.01f
#define TOLV 0.001f
#define MAXIT 10
#define ROWS 4                  // rows per block strip
#define NCHUNK (NH / ROWS)      // 128 strips per batch
#define NTHREADS 256
#define COMP_STRIDE (NB * NCHUNK)

// ws layout:
//   [0 .. 5*NB*NCHUNK) doubles : partial sums, layout [comp][b][strip]
//   PWS_OFF : 32 floats : current p
//   ERR_OFF : 1 float   : current err
#define PARTIALS_N (5 * NB * NCHUNK)
#define PWS_OFF (PARTIALS_N * 8)
#define ERR_OFF (PWS_OFF + 32 * 4)

__device__ __forceinline__ float cubicf(float t) {
    float a = fabsf(t);
    float a2 = a * a;
    float a3 = a2 * a;
    if (a <= 1.0f) return 1.5f * a3 - 2.5f * a2 + 1.0f;
    if (a < 2.0f)  return -0.5f * a3 + 2.5f * a2 - 4.0f * a + 2.0f;
    return 0.0f;
}

// Per-column bicubic weights + clamped tap indices, bit-identical to reference
__device__ __forceinline__ void col_setup(int c, float tx, float* wx, int* xi) {
    float gx = (float)c + tx;
    float fx = floorf(gx);
    int x0 = (int)fx;
    float dx = gx - fx;
    wx[0] = cubicf(dx + 1.0f);
    wx[1] = cubicf(dx);
    wx[2] = cubicf(dx - 1.0f);
    wx[3] = cubicf(dx - 2.0f);
#pragma unroll
    for (int i = 0; i < 4; ++i) xi[i] = min(max(x0 - 1 + i, 0), NW - 1);
}

__global__ __launch_bounds__(64) void gn_init(const float* __restrict__ p_in,
                                              float* __restrict__ pws,
                                              float* __restrict__ errws) {
    int t = threadIdx.x;
    if (t < 2 * NB) pws[t] = p_in[t];
    if (t == 0) errws[0] = 1e10f;
}

__global__ __launch_bounds__(NTHREADS) void gn_reduce(const float* __restrict__ I1,
                                                      const float* __restrict__ I2,
                                                      const float* __restrict__ pws,
                                                      double* __restrict__ partials) {
    const int b = blockIdx.y;
    const int strip = blockIdx.x;
    const int tid = threadIdx.x;
    const float tx = pws[2 * b];
    const float ty = pws[2 * b + 1];
    const float* I1b = I1 + (size_t)b * NHW;
    const float* I2b = I2 + (size_t)b * NHW;

    const int cA = 2 * tid;
    const int cB = 2 * tid + 1;
    float wxA[4], wxB[4];
    int xiA[4], xiB[4];
    col_setup(cA, tx, wxA, xiA);
    col_setup(cB, tx, wxB, xiB);

    __shared__ float wyS[ROWS][4];
    __shared__ int   yjS[ROWS][4];
    __shared__ int   alignS[ROWS];
    __shared__ float V[2][NW];

    const int y0row = strip * ROWS;
    if (tid < ROWS) {
        int y = y0row + tid;
        float gy = (float)y + ty;
        float fy = floorf(gy);
        int yy0 = (int)fy;
        float dy = gy - fy;
        wyS[tid][0] = cubicf(dy + 1.0f);
        wyS[tid][1] = cubicf(dy);
        wyS[tid][2] = cubicf(dy - 1.0f);
        wyS[tid][3] = cubicf(dy - 2.0f);
        int yj[4], yk[4];
#pragma unroll
        for (int i = 0; i < 4; ++i) yj[i] = min(max(yy0 - 1 + i, 0), NH - 1);
        float gy2 = (float)(y + 1) + ty;
        int yy1 = (int)floorf(gy2);
#pragma unroll
        for (int i = 0; i < 4; ++i) yk[i] = min(max(yy1 - 1 + i, 0), NH - 1);
#pragma unroll
        for (int i = 0; i < 4; ++i) yjS[tid][i] = yj[i];
        alignS[tid] = (yk[0] == yj[1]) && (yk[1] == yj[2]) && (yk[2] == yj[3]);
    }

    // I1 rolling rows (for gradients): prev / cur / staged-next
    float2 ccPrev = make_float2(0.0f, 0.0f);
    if (y0row > 0) ccPrev = *(const float2*)(I1b + (size_t)(y0row - 1) * NW + cA);
    float2 ccCur = *(const float2*)(I1b + (size_t)y0row * NW + cA);
    float2 ccNextP = *(const float2*)(I1b + (size_t)min(y0row + 1, NH - 1) * NW + cA);

    __syncthreads();   // wyS / yjS / alignS visible

    // I2 vertical tap window for output row 0 of the strip (coalesced float2)
    float2 w0 = ((const float2*)(I2b + (size_t)yjS[0][0] * NW))[tid];
    float2 w1 = ((const float2*)(I2b + (size_t)yjS[0][1] * NW))[tid];
    float2 w2 = ((const float2*)(I2b + (size_t)yjS[0][2] * NW))[tid];
    float2 w3p = ((const float2*)(I2b + (size_t)yjS[0][3] * NW))[tid];

    float a0 = 0.f, a1 = 0.f, a2 = 0.f, a3 = 0.f, a4 = 0.f;

#pragma unroll
    for (int r = 0; r < ROWS; ++r) {
        const int y = y0row + r;

        // stage next-iteration loads (issue early, consume next iter)
        float2 nI2 = make_float2(0.0f, 0.0f);
        if (r + 1 < ROWS)
            nI2 = ((const float2*)(I2b + (size_t)yjS[r + 1][3] * NW))[tid];
        float2 ncc = ((const float2*)(I1b + (size_t)min(y + 2, NH - 1) * NW))[tid];

        // vertical pass (registers ready from previous iteration)
        float2 w3 = w3p;
        const float wy0 = wyS[r][0], wy1 = wyS[r][1], wy2 = wyS[r][2], wy3 = wyS[r][3];
        float* Vb = V[r & 1];
        Vb[cA] = wy0 * w0.x + wy1 * w1.x + wy2 * w2.x + wy3 * w3.x;
        Vb[cB] = wy0 * w0.y + wy1 * w1.y + wy2 * w2.y + wy3 * w3.y;

        // I1 gradients from registers + cross-lane (pre-barrier work)
        float2 ccNext = ccNextP;
        const float* I1r = I1b + (size_t)y * NW;
        float left = __shfl_up(ccCur.y, 1);
        if ((tid & 63) == 0) left = (tid > 0) ? I1r[cA - 1] : 0.0f;
        float right = __shfl_down(ccCur.x, 1);
        if ((tid & 63) == 63) right = (tid < NTHREADS - 1) ? I1r[cB + 1] : 0.0f;
        float IxA = (cA >= 1) ? 0.5f * (ccCur.y - left) : 0.0f;
        float IxB = (cB <= NW - 2) ? 0.5f * (right - ccCur.x) : 0.0f;
        float IyA = 0.0f, IyB = 0.0f;
        if (y >= 1 && y <= NH - 2) {
            IyA = 0.5f * (ccNext.x - ccPrev.x);
            IyB = 0.5f * (ccNext.y - ccPrev.y);
        }
        __syncthreads();

        // horizontal pass + robust stats
        float IwA = wxA[0] * Vb[xiA[0]] + wxA[1] * Vb[xiA[1]] +
                    wxA[2] * Vb[xiA[2]] + wxA[3] * Vb[xiA[3]];
        float IwB = wxB[0] * Vb[xiB[0]] + wxB[1] * Vb[xiB[1]] +
                    wxB[2] * Vb[xiB[2]] + wxB[3] * Vb[xiB[3]];

        float DIA = IwA - ccCur.x, DIB = IwB - ccCur.y;
        float rhoA = 1.0f / sqrtf(DIA * DIA + LAM2);
        float rhoB = 1.0f / sqrtf(DIB * DIB + LAM2);
        float drA = DIA * rhoA, drB = DIB * rhoB;

        // f32 inner accumulation (8 px per thread; widened to f64 at reduce)
        a0 += IxA * IxA * rhoA + IxB * IxB * rhoB;
        a1 += IxA * IyA * rhoA + IxB * IyB * rhoB;
        a2 += IyA * IyA * rhoA + IyB * IyB * rhoB;
        a3 += IxA * drA + IxB * drB;
        a4 += IyA * drA + IyB * drB;

        // roll windows
        if (r + 1 < ROWS) {
            if (alignS[r]) {
                w0 = w1; w1 = w2; w2 = w3; w3p = nI2;
            } else {  // clamped border strips only; reload window
                w0 = ((const float2*)(I2b + (size_t)yjS[r + 1][0] * NW))[tid];
                w1 = ((const float2*)(I2b + (size_t)yjS[r + 1][1] * NW))[tid];
                w2 = ((const float2*)(I2b + (size_t)yjS[r + 1][2] * NW))[tid];
                w3p = nI2;
            }
        }
        ccPrev = ccCur; ccCur = ccNext; ccNextP = ncc;
        // V double-buffered: this buffer is rewritten only after the next barrier
    }

    // widen to f64, wave butterfly, LDS cross-wave
    double d0 = a0, d1 = a1, d2 = a2, d3 = a3, d4 = a4;
#pragma unroll
    for (int off = 32; off > 0; off >>= 1) {
        d0 += __shfl_down(d0, off);
        d1 += __shfl_down(d1, off);
        d2 += __shfl_down(d2, off);
        d3 += __shfl_down(d3, off);
        d4 += __shfl_down(d4, off);
    }

    __shared__ double wsum[NTHREADS / 64][5];
    int wave = tid >> 6, lane = tid & 63;
    if (lane == 0) {
        wsum[wave][0] = d0; wsum[wave][1] = d1; wsum[wave][2] = d2;
        wsum[wave][3] = d3; wsum[wave][4] = d4;
    }
    __syncthreads();
    if (tid < 5) {
        double s = wsum[0][tid] + wsum[1][tid] + wsum[2][tid] + wsum[3][tid];
        partials[(size_t)tid * COMP_STRIDE + b * NCHUNK + strip] = s;
    }
}

__global__ __launch_bounds__(128) void gn_update(const double* __restrict__ partials,
                                                 float* __restrict__ pws,
                                                 float* __restrict__ errws,
                                                 float* __restrict__ out,
                                                 int write_out) {
    __shared__ double Hs[NB][5];
    __shared__ float dpf[NB][2];
    __shared__ float pnew[2 * NB];
    const int tid = threadIdx.x;

    if (tid < NB * 5) {
        int bb = tid & 15, comp = tid >> 4;
        const double* src = partials + (size_t)comp * COMP_STRIDE + bb * NCHUNK;
        double s = 0;
#pragma unroll 8
        for (int ch = 0; ch < NCHUNK; ++ch) s += src[ch];
        Hs[bb][comp] = s;
    }
    __syncthreads();

    if (tid < NB) {
        double H00 = Hs[tid][0], H01 = Hs[tid][1], H11 = Hs[tid][2];
        double b0 = Hs[tid][3], b1 = Hs[tid][4];
        double inv = 1.0 / (H00 * H11 - H01 * H01);
        double dp0 = ( H11 * b0 - H01 * b1) * inv;
        double dp1 = (-H01 * b0 + H00 * b1) * inv;
        dpf[tid][0] = (float)dp0;
        dpf[tid][1] = (float)dp1;
    }
    __syncthreads();

    float err_old = errws[0];
    bool active = err_old > TOLV;

    if (tid < 2 * NB) {
        float pv = pws[tid];
        if (active) pv -= dpf[tid >> 1][tid & 1];
        pnew[tid] = pv;
        pws[tid] = pv;
    }

    float err_new = err_old;
    if (tid == 0) {
        if (active) {
            double n = 0;
            for (int i = 0; i < NB; ++i) {
                n += (double)dpf[i][0] * (double)dpf[i][0];
                n += (double)dpf[i][1] * (double)dpf[i][1];
            }
            err_new = (float)sqrt(n);
            errws[0] = err_new;
        }
    }
    __syncthreads();
    if (write_out) {
        if (tid < 2 * NB) out[tid] = pnew[tid];
        if (tid == 0) out[2 * NB] = err_new;
    }
}

__global__ __launch_bounds__(NTHREADS) void gn_final(const float* __restrict__ I1,
                                                     const float* __restrict__ I2,
                                                     const float* __restrict__ pws,
                                                     float* __restrict__ out) {
    const int b = blockIdx.y;
    const int strip = blockIdx.x;
    const int tid = threadIdx.x;
    const float tx = pws[2 * b];
    const float ty = pws[2 * b + 1];
    const float* I1b = I1 + (size_t)b * NHW;
    const float* I2b = I2 + (size_t)b * NHW;

    float* DIout = out + 33;
    float* IWout = out + 33 + (size_t)NB * NHW;

    const int cA = 2 * tid;
    const int cB = 2 * tid + 1;
    float wxA[4], wxB[4];
    int xiA[4], xiB[4];
    col_setup(cA, tx, wxA, xiA);
    col_setup(cB, tx, wxB, xiB);

    __shared__ float wyS[ROWS][4];
    __shared__ int   yjS[ROWS][4];
    __shared__ int   alignS[ROWS];
    __shared__ float V[2][NW];

    const int y0row = strip * ROWS;
    if (tid < ROWS) {
        int y = y0row + tid;
        float gy = (float)y + ty;
        float fy = floorf(gy);
        int yy0 = (int)fy;
        float dy = gy - fy;
        wyS[tid][0] = cubicf(dy + 1.0f);
        wyS[tid][1] = cubicf(dy);
        wyS[tid][2] = cubicf(dy - 1.0f);
        wyS[tid][3] = cubicf(dy - 2.0f);
        int yj[4], yk[4];
#pragma unroll
        for (int i = 0; i < 4; ++i) yj[i] = min(max(yy0 - 1 + i, 0), NH - 1);
        float gy2 = (float)(y + 1) + ty;
        int yy1 = (int)floorf(gy2);
#pragma unroll
        for (int i = 0; i < 4; ++i) yk[i] = min(max(yy1 - 1 + i, 0), NH - 1);
#pragma unroll
        for (int i = 0; i < 4; ++i) yjS[tid][i] = yj[i];
        alignS[tid] = (yk[0] == yj[1]) && (yk[1] == yj[2]) && (yk[2] == yj[3]);
    }

    float2 ccP = *(const float2*)(I1b + (size_t)y0row * NW + cA);
    __syncthreads();

    float2 w0 = ((const float2*)(I2b + (size_t)yjS[0][0] * NW))[tid];
    float2 w1 = ((const float2*)(I2b + (size_t)yjS[0][1] * NW))[tid];
    float2 w2 = ((const float2*)(I2b + (size_t)yjS[0][2] * NW))[tid];
    float2 w3p = ((const float2*)(I2b + (size_t)yjS[0][3] * NW))[tid];

#pragma unroll
    for (int r = 0; r < ROWS; ++r) {
        const int y = y0row + r;

        float2 nI2 = make_float2(0.0f, 0.0f);
        if (r + 1 < ROWS)
            nI2 = ((const float2*)(I2b + (size_t)yjS[r + 1][3] * NW))[tid];
        float2 ncc = make_float2(0.0f, 0.0f);
        if (r + 1 < ROWS)
            ncc = *(const float2*)(I1b + (size_t)(y + 1) * NW + cA);

        float2 w3 = w3p;
        const float wy0 = wyS[r][0], wy1 = wyS[r][1], wy2 = wyS[r][2], wy3 = wyS[r][3];
        float* Vb = V[r & 1];
        Vb[cA] = wy0 * w0.x + wy1 * w1.x + wy2 * w2.x + wy3 * w3.x;
        Vb[cB] = wy0 * w0.y + wy1 * w1.y + wy2 * w2.y + wy3 * w3.y;

        float2 cc = ccP;
        __syncthreads();

        float IwA = wxA[0] * Vb[xiA[0]] + wxA[1] * Vb[xiA[1]] +
                    wxA[2] * Vb[xiA[2]] + wxA[3] * Vb[xiA[3]];
        float IwB = wxB[0] * Vb[xiB[0]] + wxB[1] * Vb[xiB[1]] +
                    wxB[2] * Vb[xiB[2]] + wxB[3] * Vb[xiB[3]];

        size_t o = (size_t)b * NHW + (size_t)y * NW + cA;
        float2 dv; dv.x = IwA - cc.x; dv.y = IwB - cc.y;
        float2 wv; wv.x = IwA; wv.y = IwB;
        *(float2*)(DIout + o) = dv;
        *(float2*)(IWout + o) = wv;

        if (r + 1 < ROWS) {
            if (alignS[r]) {
                w0 = w1; w1 = w2; w2 = w3; w3p = nI2;
            } else {
                w0 = ((const float2*)(I2b + (size_t)yjS[r + 1][0] * NW))[tid];
                w1 = ((const float2*)(I2b + (size_t)yjS[r + 1][1] * NW))[tid];
                w2 = ((const float2*)(I2b + (size_t)yjS[r + 1][2] * NW))[tid];
                w3p = nI2;
            }
        }
        ccP = ncc;
    }
}

extern "C" void kernel_launch(void* const* d_in, const int* in_sizes, int n_in,
                              void* d_out, int out_size, void* d_ws, size_t ws_size,
                              hipStream_t stream) {
    const float* I1 = (const float*)d_in[0];
    const float* I2 = (const float*)d_in[1];
    const float* p  = (const float*)d_in[2];
    float* out = (float*)d_out;

    double* partials = (double*)d_ws;
    float* pws   = (float*)((char*)d_ws + PWS_OFF);
    float* errws = (float*)((char*)d_ws + ERR_OFF);

    gn_init<<<1, 64, 0, stream>>>(p, pws, errws);

    dim3 grid(NCHUNK, NB);
    for (int t = 0; t < MAXIT; ++t) {
        gn_reduce<<<grid, NTHREADS, 0, stream>>>(I1, I2, pws, partials);
        gn_update<<<1, 128, 0, stream>>>(partials, pws, errws, out, (t == MAXIT - 1) ? 1 : 0);
    }
    gn_final<<<grid, NTHREADS, 0, stream>>>(I1, I2, pws, out);
}

// Round 8
// 251.821 us; speedup vs baseline: 1.3854x; 1.0502x over previous
//
#include <hip/hip_runtime.h>
#include <math.h>

#define NB 16
#define NH 512
#define NW 512
#define NHW (NH * NW)
#define LAM2 0.01f
#define TOLV 0.001f
#define MAXIT 10
#define ROWS 8                  // rows per block strip
#define NCHUNK (NH / ROWS)      // 64 strips per batch
#define NTHREADS 256
#define COMP_STRIDE (NB * NCHUNK)

// ws layout:
//   [0 .. 5*NB*NCHUNK) doubles : partial sums, layout [comp][b][strip]
//   PWS_OFF : 32 floats : current p
//   ERR_OFF : 1 float   : current err
#define PARTIALS_N (5 * NB * NCHUNK)
#define PWS_OFF (PARTIALS_N * 8)
#define ERR_OFF (PWS_OFF + 32 * 4)

__device__ __forceinline__ float cubicf(float t) {
    float a = fabsf(t);
    float a2 = a * a;
    float a3 = a2 * a;
    if (a <= 1.0f) return 1.5f * a3 - 2.5f * a2 + 1.0f;
    if (a < 2.0f)  return -0.5f * a3 + 2.5f * a2 - 4.0f * a + 2.0f;
    return 0.0f;
}

// Per-column bicubic weights + clamped tap indices, bit-identical to reference
__device__ __forceinline__ void col_setup(int c, float tx, float* wx, int* xi) {
    float gx = (float)c + tx;
    float fx = floorf(gx);
    int x0 = (int)fx;
    float dx = gx - fx;
    wx[0] = cubicf(dx + 1.0f);
    wx[1] = cubicf(dx);
    wx[2] = cubicf(dx - 1.0f);
    wx[3] = cubicf(dx - 2.0f);
#pragma unroll
    for (int i = 0; i < 4; ++i) xi[i] = min(max(x0 - 1 + i, 0), NW - 1);
}

__device__ __forceinline__ float4 ld4(const float* __restrict__ p, int row, int t) {
    return ((const float4*)(p + (size_t)row * NW))[t];
}

__global__ __launch_bounds__(64) void gn_init(const float* __restrict__ p_in,
                                              float* __restrict__ pws,
                                              float* __restrict__ errws) {
    int t = threadIdx.x;
    if (t < 2 * NB) pws[t] = p_in[t];
    if (t == 0) errws[0] = 1e10f;
}

// 4 columns/thread (float4), two 128-thread groups do rows (2s+h); 4 barriers.
__global__ __launch_bounds__(NTHREADS) void gn_reduce(const float* __restrict__ I1,
                                                      const float* __restrict__ I2,
                                                      const float* __restrict__ pws,
                                                      double* __restrict__ partials) {
    const int b = blockIdx.y;
    const int strip = blockIdx.x;
    const int tid = threadIdx.x;
    const int h = tid >> 7;          // row-parity group
    const int t = tid & 127;         // thread within group
    const int c0 = 4 * t;
    const float tx = pws[2 * b];
    const float ty = pws[2 * b + 1];
    const float* I1b = I1 + (size_t)b * NHW;
    const float* I2b = I2 + (size_t)b * NHW;

    float wx[4][4];
    int xi[4][4];
#pragma unroll
    for (int j = 0; j < 4; ++j) col_setup(c0 + j, tx, wx[j], xi[j]);
    const int base = xi[0][0];
    bool fast = true;
#pragma unroll
    for (int j = 0; j < 4; ++j)
#pragma unroll
        for (int i = 0; i < 4; ++i)
            fast = fast && (xi[j][i] == base + j + i);
    const int s = base & 3;
    const int wbase = base - s;      // 16B-aligned float index into V row

    __shared__ float wyS[ROWS][4];
    __shared__ int   yjS[ROWS][4];
    __shared__ int   align2S[ROWS];
    __shared__ float V[2][2][NW + 8];   // [step&1][group][cols+pad]

    const int y0row = strip * ROWS;
    if (tid < ROWS) {
        int y = y0row + tid;
        float gy = (float)y + ty;
        float fy = floorf(gy);
        int yy0 = (int)fy;
        float dy = gy - fy;
        wyS[tid][0] = cubicf(dy + 1.0f);
        wyS[tid][1] = cubicf(dy);
        wyS[tid][2] = cubicf(dy - 1.0f);
        wyS[tid][3] = cubicf(dy - 2.0f);
        int yj[4], yk[4];
#pragma unroll
        for (int i = 0; i < 4; ++i) yj[i] = min(max(yy0 - 1 + i, 0), NH - 1);
        // taps of row (this+2) for the roll-by-2 alignment flag
        float gy2 = (float)(y + 2) + ty;
        int yy2 = (int)floorf(gy2);
#pragma unroll
        for (int i = 0; i < 4; ++i) yk[i] = min(max(yy2 - 1 + i, 0), NH - 1);
#pragma unroll
        for (int i = 0; i < 4; ++i) yjS[tid][i] = yj[i];
        align2S[tid] = (yk[0] == yj[2]) && (yk[1] == yj[3]) ? 1 : 0;
    }
    __syncthreads();

    // initial windows for this group's first row (y0row + h)
    const int yA = y0row + h;
    float4 w0 = ld4(I2b, yjS[h][0], t);
    float4 w1 = ld4(I2b, yjS[h][1], t);
    float4 w2 = ld4(I2b, yjS[h][2], t);
    float4 w3 = ld4(I2b, yjS[h][3], t);
    float4 ccPrev = ld4(I1b, max(yA - 1, 0), t);
    float4 ccCur  = ld4(I1b, yA, t);
    float4 ccNext = ld4(I1b, min(yA + 1, NH - 1), t);

    float a0 = 0.f, a1 = 0.f, a2 = 0.f, a3 = 0.f, a4 = 0.f;

#pragma unroll
    for (int st = 0; st < 4; ++st) {
        const int r = 2 * st + h;
        const int y = y0row + r;

        // ---- prefetch next step's rows (consumed after the barrier) ----
        float4 nw0, nw1, nw2, nw3, nccC, nccN;
        bool rollAligned = true;
        if (st < 3) {
            const int rn = r + 2;
            rollAligned = (align2S[r] != 0);
            nw2 = ld4(I2b, yjS[rn][2], t);
            nw3 = ld4(I2b, yjS[rn][3], t);
            if (!rollAligned) {          // border strips only
                nw0 = ld4(I2b, yjS[rn][0], t);
                nw1 = ld4(I2b, yjS[rn][1], t);
            }
            nccC = ld4(I1b, min(y + 2, NH - 1), t);
            nccN = ld4(I1b, min(y + 3, NH - 1), t);
        }

        // ---- vertical combine -> LDS ----
        const float wy0 = wyS[r][0], wy1 = wyS[r][1], wy2v = wyS[r][2], wy3v = wyS[r][3];
        float4 V4;
        V4.x = wy0 * w0.x + wy1 * w1.x + wy2v * w2.x + wy3v * w3.x;
        V4.y = wy0 * w0.y + wy1 * w1.y + wy2v * w2.y + wy3v * w3.y;
        V4.z = wy0 * w0.z + wy1 * w1.z + wy2v * w2.z + wy3v * w3.z;
        V4.w = wy0 * w0.w + wy1 * w1.w + wy2v * w2.w + wy3v * w3.w;
        float* Vb = V[st & 1][h];
        ((float4*)Vb)[t] = V4;

        // ---- I1 gradients (pre-barrier, registers + cross-lane) ----
        const float* I1r = I1b + (size_t)y * NW;
        float left = __shfl_up(ccCur.w, 1);
        if ((t & 63) == 0) left = (c0 >= 1) ? I1r[c0 - 1] : 0.0f;
        float right = __shfl_down(ccCur.x, 1);
        if ((t & 63) == 63) right = (c0 + 4 <= NW - 1) ? I1r[c0 + 4] : 0.0f;

        float Ixv[4], Iyv[4], ccA[4], cpA[4], cnA[4];
        ccA[0] = ccCur.x; ccA[1] = ccCur.y; ccA[2] = ccCur.z; ccA[3] = ccCur.w;
        cpA[0] = ccPrev.x; cpA[1] = ccPrev.y; cpA[2] = ccPrev.z; cpA[3] = ccPrev.w;
        cnA[0] = ccNext.x; cnA[1] = ccNext.y; cnA[2] = ccNext.z; cnA[3] = ccNext.w;
        Ixv[0] = (c0 >= 1) ? 0.5f * (ccA[1] - left) : 0.0f;
        Ixv[1] = 0.5f * (ccA[2] - ccA[0]);
        Ixv[2] = 0.5f * (ccA[3] - ccA[1]);
        Ixv[3] = (c0 + 3 <= NW - 2) ? 0.5f * (right - ccA[2]) : 0.0f;
        const bool yint = (y >= 1 && y <= NH - 2);
#pragma unroll
        for (int j = 0; j < 4; ++j)
            Iyv[j] = yint ? 0.5f * (cnA[j] - cpA[j]) : 0.0f;

        __syncthreads();

        // ---- horizontal pass from LDS ----
        float Hc[4];
        if (fast) {
            const float4* Wp = (const float4*)(Vb + wbase);
            float4 W0 = Wp[0], W1 = Wp[1], W2 = Wp[2];
            float U0, U1, U2, U3, U4, U5, U6;
            switch (s) {
                case 0:  U0=W0.x; U1=W0.y; U2=W0.z; U3=W0.w; U4=W1.x; U5=W1.y; U6=W1.z; break;
                case 1:  U0=W0.y; U1=W0.z; U2=W0.w; U3=W1.x; U4=W1.y; U5=W1.z; U6=W1.w; break;
                case 2:  U0=W0.z; U1=W0.w; U2=W1.x; U3=W1.y; U4=W1.z; U5=W1.w; U6=W2.x; break;
                default: U0=W0.w; U1=W1.x; U2=W1.y; U3=W1.z; U4=W1.w; U5=W2.x; U6=W2.y; break;
            }
            Hc[0] = wx[0][0]*U0 + wx[0][1]*U1 + wx[0][2]*U2 + wx[0][3]*U3;
            Hc[1] = wx[1][0]*U1 + wx[1][1]*U2 + wx[1][2]*U3 + wx[1][3]*U4;
            Hc[2] = wx[2][0]*U2 + wx[2][1]*U3 + wx[2][2]*U4 + wx[2][3]*U5;
            Hc[3] = wx[3][0]*U3 + wx[3][1]*U4 + wx[3][2]*U5 + wx[3][3]*U6;
        } else {
#pragma unroll
            for (int j = 0; j < 4; ++j)
                Hc[j] = wx[j][0]*Vb[xi[j][0]] + wx[j][1]*Vb[xi[j][1]] +
                        wx[j][2]*Vb[xi[j][2]] + wx[j][3]*Vb[xi[j][3]];
        }

        // ---- robust stats (f32 inner accumulation) ----
#pragma unroll
        for (int j = 0; j < 4; ++j) {
            float DI = Hc[j] - ccA[j];
            float rho = 1.0f / sqrtf(DI * DI + LAM2);
            float dr = DI * rho;
            a0 += Ixv[j] * Ixv[j] * rho;
            a1 += Ixv[j] * Iyv[j] * rho;
            a2 += Iyv[j] * Iyv[j] * rho;
            a3 += Ixv[j] * dr;
            a4 += Iyv[j] * dr;
        }

        // ---- roll windows ----
        if (st < 3) {
            if (rollAligned) { w0 = w2; w1 = w3; }
            else             { w0 = nw0; w1 = nw1; }
            w2 = nw2; w3 = nw3;
            ccPrev = ccNext; ccCur = nccC; ccNext = nccN;
        }
    }

    // widen to f64, wave butterfly, cross-wave via LDS
    double d0 = a0, d1 = a1, d2 = a2, d3 = a3, d4 = a4;
#pragma unroll
    for (int off = 32; off > 0; off >>= 1) {
        d0 += __shfl_down(d0, off);
        d1 += __shfl_down(d1, off);
        d2 += __shfl_down(d2, off);
        d3 += __shfl_down(d3, off);
        d4 += __shfl_down(d4, off);
    }

    __shared__ double wsum[NTHREADS / 64][5];
    int wave = tid >> 6, lane = tid & 63;
    if (lane == 0) {
        wsum[wave][0] = d0; wsum[wave][1] = d1; wsum[wave][2] = d2;
        wsum[wave][3] = d3; wsum[wave][4] = d4;
    }
    __syncthreads();
    if (tid < 5) {
        double ssum = wsum[0][tid] + wsum[1][tid] + wsum[2][tid] + wsum[3][tid];
        partials[(size_t)tid * COMP_STRIDE + b * NCHUNK + strip] = ssum;
    }
}

__global__ __launch_bounds__(128) void gn_update(const double* __restrict__ partials,
                                                 float* __restrict__ pws,
                                                 float* __restrict__ errws,
                                                 float* __restrict__ out,
                                                 int write_out) {
    __shared__ double Hs[NB][5];
    __shared__ float dpf[NB][2];
    __shared__ float pnew[2 * NB];
    const int tid = threadIdx.x;

    if (tid < NB * 5) {
        int bb = tid & 15, comp = tid >> 4;
        const double* src = partials + (size_t)comp * COMP_STRIDE + bb * NCHUNK;
        double s = 0;
#pragma unroll 8
        for (int ch = 0; ch < NCHUNK; ++ch) s += src[ch];
        Hs[bb][comp] = s;
    }
    __syncthreads();

    if (tid < NB) {
        double H00 = Hs[tid][0], H01 = Hs[tid][1], H11 = Hs[tid][2];
        double b0 = Hs[tid][3], b1 = Hs[tid][4];
        double inv = 1.0 / (H00 * H11 - H01 * H01);
        double dp0 = ( H11 * b0 - H01 * b1) * inv;
        double dp1 = (-H01 * b0 + H00 * b1) * inv;
        dpf[tid][0] = (float)dp0;
        dpf[tid][1] = (float)dp1;
    }
    __syncthreads();

    float err_old = errws[0];
    bool active = err_old > TOLV;

    if (tid < 2 * NB) {
        float pv = pws[tid];
        if (active) pv -= dpf[tid >> 1][tid & 1];
        pnew[tid] = pv;
        pws[tid] = pv;
    }

    float err_new = err_old;
    if (tid == 0) {
        if (active) {
            double n = 0;
            for (int i = 0; i < NB; ++i) {
                n += (double)dpf[i][0] * (double)dpf[i][0];
                n += (double)dpf[i][1] * (double)dpf[i][1];
            }
            err_new = (float)sqrt(n);
            errws[0] = err_new;
        }
    }
    __syncthreads();
    if (write_out) {
        if (tid < 2 * NB) out[tid] = pnew[tid];
        if (tid == 0) out[2 * NB] = err_new;
    }
}

__global__ __launch_bounds__(NTHREADS) void gn_final(const float* __restrict__ I1,
                                                     const float* __restrict__ I2,
                                                     const float* __restrict__ pws,
                                                     float* __restrict__ out) {
    const int b = blockIdx.y;
    const int strip = blockIdx.x;
    const int tid = threadIdx.x;
    const float tx = pws[2 * b];
    const float ty = pws[2 * b + 1];
    const float* I1b = I1 + (size_t)b * NHW;
    const float* I2b = I2 + (size_t)b * NHW;

    float* DIout = out + 33;
    float* IWout = out + 33 + (size_t)NB * NHW;

    const int cA = 2 * tid;
    const int cB = 2 * tid + 1;
    float wxA[4], wxB[4];
    int xiA[4], xiB[4];
    col_setup(cA, tx, wxA, xiA);
    col_setup(cB, tx, wxB, xiB);

    __shared__ float wyS[ROWS][4];
    __shared__ int   yjS[ROWS][4];
    __shared__ int   alignS[ROWS];
    __shared__ float V[2][NW];

    const int y0row = strip * ROWS;
    if (tid < ROWS) {
        int y = y0row + tid;
        float gy = (float)y + ty;
        float fy = floorf(gy);
        int yy0 = (int)fy;
        float dy = gy - fy;
        wyS[tid][0] = cubicf(dy + 1.0f);
        wyS[tid][1] = cubicf(dy);
        wyS[tid][2] = cubicf(dy - 1.0f);
        wyS[tid][3] = cubicf(dy - 2.0f);
        int yj[4], yk[4];
#pragma unroll
        for (int i = 0; i < 4; ++i) yj[i] = min(max(yy0 - 1 + i, 0), NH - 1);
        float gy2 = (float)(y + 1) + ty;
        int yy1 = (int)floorf(gy2);
#pragma unroll
        for (int i = 0; i < 4; ++i) yk[i] = min(max(yy1 - 1 + i, 0), NH - 1);
#pragma unroll
        for (int i = 0; i < 4; ++i) yjS[tid][i] = yj[i];
        alignS[tid] = (yk[0] == yj[1]) && (yk[1] == yj[2]) && (yk[2] == yj[3]);
    }

    float2 ccP = *(const float2*)(I1b + (size_t)y0row * NW + cA);
    __syncthreads();

    float2 w0 = ((const float2*)(I2b + (size_t)yjS[0][0] * NW))[tid];
    float2 w1 = ((const float2*)(I2b + (size_t)yjS[0][1] * NW))[tid];
    float2 w2 = ((const float2*)(I2b + (size_t)yjS[0][2] * NW))[tid];
    float2 w3p = ((const float2*)(I2b + (size_t)yjS[0][3] * NW))[tid];

#pragma unroll
    for (int r = 0; r < ROWS; ++r) {
        const int y = y0row + r;

        float2 nI2 = make_float2(0.0f, 0.0f);
        if (r + 1 < ROWS)
            nI2 = ((const float2*)(I2b + (size_t)yjS[r + 1][3] * NW))[tid];
        float2 ncc = make_float2(0.0f, 0.0f);
        if (r + 1 < ROWS)
            ncc = *(const float2*)(I1b + (size_t)(y + 1) * NW + cA);

        float2 w3 = w3p;
        const float wy0 = wyS[r][0], wy1 = wyS[r][1], wy2 = wyS[r][2], wy3 = wyS[r][3];
        float* Vb = V[r & 1];
        Vb[cA] = wy0 * w0.x + wy1 * w1.x + wy2 * w2.x + wy3 * w3.x;
        Vb[cB] = wy0 * w0.y + wy1 * w1.y + wy2 * w2.y + wy3 * w3.y;

        float2 cc = ccP;
        __syncthreads();

        float IwA = wxA[0] * Vb[xiA[0]] + wxA[1] * Vb[xiA[1]] +
                    wxA[2] * Vb[xiA[2]] + wxA[3] * Vb[xiA[3]];
        float IwB = wxB[0] * Vb[xiB[0]] + wxB[1] * Vb[xiB[1]] +
                    wxB[2] * Vb[xiB[2]] + wxB[3] * Vb[xiB[3]];

        size_t o = (size_t)b * NHW + (size_t)y * NW + cA;
        float2 dv; dv.x = IwA - cc.x; dv.y = IwB - cc.y;
        float2 wv; wv.x = IwA; wv.y = IwB;
        *(float2*)(DIout + o) = dv;
        *(float2*)(IWout + o) = wv;

        if (r + 1 < ROWS) {
            if (alignS[r]) {
                w0 = w1; w1 = w2; w2 = w3; w3p = nI2;
            } else {
                w0 = ((const float2*)(I2b + (size_t)yjS[r + 1][0] * NW))[tid];
                w1 = ((const float2*)(I2b + (size_t)yjS[r + 1][1] * NW))[tid];
                w2 = ((const float2*)(I2b + (size_t)yjS[r + 1][2] * NW))[tid];
                w3p = nI2;
            }
        }
        ccP = ncc;
    }
}

extern "C" void kernel_launch(void* const* d_in, const int* in_sizes, int n_in,
                              void* d_out, int out_size, void* d_ws, size_t ws_size,
                              hipStream_t stream) {
    const float* I1 = (const float*)d_in[0];
    const float* I2 = (const float*)d_in[1];
    const float* p  = (const float*)d_in[2];
    float* out = (float*)d_out;

    double* partials = (double*)d_ws;
    float* pws   = (float*)((char*)d_ws + PWS_OFF);
    float* errws = (float*)((char*)d_ws + ERR_OFF);

    gn_init<<<1, 64, 0, stream>>>(p, pws, errws);

    dim3 grid(NCHUNK, NB);
    for (int t = 0; t < MAXIT; ++t) {
        gn_reduce<<<grid, NTHREADS, 0, stream>>>(I1, I2, pws, partials);
        gn_update<<<1, 128, 0, stream>>>(partials, pws, errws, out, (t == MAXIT - 1) ? 1 : 0);
    }
    gn_final<<<grid, NTHREADS, 0, stream>>>(I1, I2, pws, out);
}

// Round 9
// 190.260 us; speedup vs baseline: 1.8337x; 1.3236x over previous
//
#include <hip/hip_runtime.h>
#include <math.h>

#define NB 16
#define NH 512
#define NW 512
#define NHW (NH * NW)
#define LAM2 0.01f
#define TOLV 0.001f
#define MAXIT 10
#define ROWS 16                 // rows per block strip
#define RPW 4                   // rows per wave (4 waves/block)
#define NCHUNK (NH / ROWS)      // 32 strips per batch
#define NTHREADS 256
#define COMP_STRIDE (NB * NCHUNK)

#define PARTIALS_N (5 * NB * NCHUNK)
#define PWS_OFF (PARTIALS_N * 8)
#define ERR_OFF (PWS_OFF + 32 * 4)

__device__ __forceinline__ float cubicf(float t) {
    float a = fabsf(t);
    float a2 = a * a;
    float a3 = a2 * a;
    if (a <= 1.0f) return 1.5f * a3 - 2.5f * a2 + 1.0f;
    if (a < 2.0f)  return -0.5f * a3 + 2.5f * a2 - 4.0f * a + 2.0f;
    return 0.0f;
}

__device__ __forceinline__ int clampy(int v) { return min(max(v, 0), NH - 1); }
__device__ __forceinline__ int clampx(int v) { return min(max(v, 0), NW - 1); }

__device__ __forceinline__ float4 L4(const float* __restrict__ p, int row, int i) {
    return ((const float4*)(p + (size_t)row * NW))[i];
}

__device__ __forceinline__ void unpack8(const float4& A, const float4& B, float* o) {
    o[0] = A.x; o[1] = A.y; o[2] = A.z; o[3] = A.w;
    o[4] = B.x; o[5] = B.y; o[6] = B.z; o[7] = B.w;
}

__global__ __launch_bounds__(64) void gn_init(const float* __restrict__ p_in,
                                              float* __restrict__ pws,
                                              float* __restrict__ errws) {
    int t = threadIdx.x;
    if (t < 2 * NB) pws[t] = p_in[t];
    if (t == 0) errws[0] = 1e10f;
}

// Wave-private rows: each wave owns RPW full rows; zero barriers in main loop.
// Lane covers 8 cols; V kept in a per-wave LDS row with replicated-edge halo.
__global__ __launch_bounds__(NTHREADS) void gn_reduce(const float* __restrict__ I1,
                                                      const float* __restrict__ I2,
                                                      const float* __restrict__ pws,
                                                      double* __restrict__ partials) {
    const int b = blockIdx.y;
    const int strip = blockIdx.x;
    const int tid = threadIdx.x;
    const int wv = tid >> 6, lane = tid & 63;
    const int c0 = 8 * lane;
    const float tx = pws[2 * b];
    const float ty = pws[2 * b + 1];
    const float* I1b = I1 + (size_t)b * NHW;
    const float* I2b = I2 + (size_t)b * NHW;

    // ---- horizontal setup: weights once per lane, exact per-col floor check ----
    float gx0 = (float)c0 + tx;
    float fx0 = floorf(gx0);
    float dx0 = gx0 - fx0;
    int x00 = (int)fx0;
    const float wx0 = cubicf(dx0 + 1.0f), wx1 = cubicf(dx0);
    const float wx2 = cubicf(dx0 - 1.0f), wx3 = cubicf(dx0 - 2.0f);
    bool fast = true;
#pragma unroll
    for (int j = 1; j < 8; ++j) {
        int xj = (int)floorf((float)(c0 + j) + tx);
        fast = fast && (xj == x00 + j);
    }
    const int base = x00 - 1;                 // taps span base..base+10
    fast = fast && (base >= -8) && (base + 10 <= NW + 7);   // inside halo
    const int s = base & 3;
    const int wbase = base - s;               // 4-aligned

    __shared__ float VS[4][NW + 24];          // [wave][8 halo | 512 | 8 halo | pad]
    float* Vw = VS[wv];

    const int ybase = strip * ROWS + wv * RPW;

    // vertical taps for first row
    int yj0, yj1, yj2, yj3;
    {
        int yy = (int)floorf((float)ybase + ty);
        yj0 = clampy(yy - 1); yj1 = clampy(yy);
        yj2 = clampy(yy + 1); yj3 = clampy(yy + 2);
    }
    float4 w0a = L4(I2b, yj0, 2 * lane), w0b = L4(I2b, yj0, 2 * lane + 1);
    float4 w1a = L4(I2b, yj1, 2 * lane), w1b = L4(I2b, yj1, 2 * lane + 1);
    float4 w2a = L4(I2b, yj2, 2 * lane), w2b = L4(I2b, yj2, 2 * lane + 1);
    float4 w3a = L4(I2b, yj3, 2 * lane), w3b = L4(I2b, yj3, 2 * lane + 1);

    // I1 rolling rows
    float4 cpa = L4(I1b, max(ybase - 1, 0), 2 * lane), cpb = L4(I1b, max(ybase - 1, 0), 2 * lane + 1);
    float4 cca = L4(I1b, ybase, 2 * lane),             ccb = L4(I1b, ybase, 2 * lane + 1);
    float4 cna = L4(I1b, min(ybase + 1, NH - 1), 2 * lane), cnb = L4(I1b, min(ybase + 1, NH - 1), 2 * lane + 1);

    float a0 = 0.f, a1 = 0.f, a2 = 0.f, a3 = 0.f, a4 = 0.f;

#pragma unroll
    for (int r = 0; r < RPW; ++r) {
        const int y = ybase + r;

        // wy weights (per-lane, redundant, no LDS)
        float gy = (float)y + ty, fy = floorf(gy), dy = gy - fy;
        const float wy0 = cubicf(dy + 1.0f), wy1 = cubicf(dy);
        const float wy2 = cubicf(dy - 1.0f), wy3 = cubicf(dy - 2.0f);

        // next-row taps + prefetch (issued early, consumed at roll)
        int nyj0 = 0, nyj1 = 0, nyj2 = 0, nyj3 = 0;
        bool aligned = true;
        float4 nta, ntb, n1a, n1b;
        if (r + 1 < RPW) {
            int yy2 = (int)floorf((float)(y + 1) + ty);
            nyj0 = clampy(yy2 - 1); nyj1 = clampy(yy2);
            nyj2 = clampy(yy2 + 1); nyj3 = clampy(yy2 + 2);
            aligned = (nyj0 == yj1) && (nyj1 == yj2) && (nyj2 == yj3);
            nta = L4(I2b, nyj3, 2 * lane); ntb = L4(I2b, nyj3, 2 * lane + 1);
            n1a = L4(I1b, min(y + 2, NH - 1), 2 * lane);
            n1b = L4(I1b, min(y + 2, NH - 1), 2 * lane + 1);
        }

        // vertical combine -> wave-private LDS (+ halo)
        float4 Va, Vb;
        Va.x = wy0 * w0a.x + wy1 * w1a.x + wy2 * w2a.x + wy3 * w3a.x;
        Va.y = wy0 * w0a.y + wy1 * w1a.y + wy2 * w2a.y + wy3 * w3a.y;
        Va.z = wy0 * w0a.z + wy1 * w1a.z + wy2 * w2a.z + wy3 * w3a.z;
        Va.w = wy0 * w0a.w + wy1 * w1a.w + wy2 * w2a.w + wy3 * w3a.w;
        Vb.x = wy0 * w0b.x + wy1 * w1b.x + wy2 * w2b.x + wy3 * w3b.x;
        Vb.y = wy0 * w0b.y + wy1 * w1b.y + wy2 * w2b.y + wy3 * w3b.y;
        Vb.z = wy0 * w0b.z + wy1 * w1b.z + wy2 * w2b.z + wy3 * w3b.z;
        Vb.w = wy0 * w0b.w + wy1 * w1b.w + wy2 * w2b.w + wy3 * w3b.w;
        ((float4*)(Vw + 8))[2 * lane] = Va;
        ((float4*)(Vw + 8))[2 * lane + 1] = Vb;
        if (lane == 0)  { float4 h; h.x = h.y = h.z = h.w = Va.x; ((float4*)Vw)[0] = h; ((float4*)Vw)[1] = h; }
        if (lane == 63) { float4 h; h.x = h.y = h.z = h.w = Vb.w; ((float4*)(Vw + 8 + NW))[0] = h; ((float4*)(Vw + 8 + NW))[1] = h; }

        // I1 gradients (registers + in-wave shfl; row edges are wave edges)
        float left = __shfl_up(ccb.w, 1);
        float right = __shfl_down(cca.x, 1);
        float cc[8], cp[8], cn[8];
        unpack8(cca, ccb, cc); unpack8(cpa, cpb, cp); unpack8(cna, cnb, cn);
        float Ix[8], Iy[8];
        Ix[0] = (lane > 0) ? 0.5f * (cc[1] - left) : 0.0f;
#pragma unroll
        for (int j = 1; j < 7; ++j) Ix[j] = 0.5f * (cc[j + 1] - cc[j - 1]);
        Ix[7] = (lane < 63) ? 0.5f * (right - cc[6]) : 0.0f;
        const bool yint = (y >= 1 && y <= NH - 2);
#pragma unroll
        for (int j = 0; j < 8; ++j) Iy[j] = yint ? 0.5f * (cn[j] - cp[j]) : 0.0f;

        // horizontal pass (same-wave LDS round-trip, lgkmcnt only)
        float Hc[8];
        if (fast) {
            const float4* Wp = (const float4*)(Vw + 8 + wbase);
            float4 W0 = Wp[0], W1 = Wp[1], W2 = Wp[2], W3 = Wp[3];
            float u0, u1, u2, u3, u4, u5, u6, u7, u8, u9, u10;
            switch (s) {
                case 0:  u0=W0.x; u1=W0.y; u2=W0.z; u3=W0.w; u4=W1.x; u5=W1.y; u6=W1.z; u7=W1.w; u8=W2.x; u9=W2.y; u10=W2.z; break;
                case 1:  u0=W0.y; u1=W0.z; u2=W0.w; u3=W1.x; u4=W1.y; u5=W1.z; u6=W1.w; u7=W2.x; u8=W2.y; u9=W2.z; u10=W2.w; break;
                case 2:  u0=W0.z; u1=W0.w; u2=W1.x; u3=W1.y; u4=W1.z; u5=W1.w; u6=W2.x; u7=W2.y; u8=W2.z; u9=W2.w; u10=W3.x; break;
                default: u0=W0.w; u1=W1.x; u2=W1.y; u3=W1.z; u4=W1.w; u5=W2.x; u6=W2.y; u7=W2.z; u8=W2.w; u9=W3.x; u10=W3.y; break;
            }
            Hc[0] = wx0*u0 + wx1*u1 + wx2*u2  + wx3*u3;
            Hc[1] = wx0*u1 + wx1*u2 + wx2*u3  + wx3*u4;
            Hc[2] = wx0*u2 + wx1*u3 + wx2*u4  + wx3*u5;
            Hc[3] = wx0*u3 + wx1*u4 + wx2*u5  + wx3*u6;
            Hc[4] = wx0*u4 + wx1*u5 + wx2*u6  + wx3*u7;
            Hc[5] = wx0*u5 + wx1*u6 + wx2*u7  + wx3*u8;
            Hc[6] = wx0*u6 + wx1*u7 + wx2*u8  + wx3*u9;
            Hc[7] = wx0*u7 + wx1*u8 + wx2*u9  + wx3*u10;
        } else {
            // exact per-col slow path (floor-flip lanes; rare)
#pragma unroll
            for (int j = 0; j < 8; ++j) {
                float g = (float)(c0 + j) + tx;
                float f = floorf(g);
                int x0 = (int)f;
                float d = g - f;
                float v0 = cubicf(d + 1.0f), v1 = cubicf(d);
                float v2 = cubicf(d - 1.0f), v3 = cubicf(d - 2.0f);
                Hc[j] = v0 * Vw[8 + clampx(x0 - 1)] + v1 * Vw[8 + clampx(x0)] +
                        v2 * Vw[8 + clampx(x0 + 1)] + v3 * Vw[8 + clampx(x0 + 2)];
            }
        }

        // robust stats (f32 inner accumulation, widened at reduce)
#pragma unroll
        for (int j = 0; j < 8; ++j) {
            float DI = Hc[j] - cc[j];
            float rho = 1.0f / sqrtf(DI * DI + LAM2);
            float dr = DI * rho;
            a0 += Ix[j] * Ix[j] * rho;
            a1 += Ix[j] * Iy[j] * rho;
            a2 += Iy[j] * Iy[j] * rho;
            a3 += Ix[j] * dr;
            a4 += Iy[j] * dr;
        }

        // roll windows
        if (r + 1 < RPW) {
            if (aligned) {
                w0a = w1a; w0b = w1b; w1a = w2a; w1b = w2b; w2a = w3a; w2b = w3b;
            } else {          // border strips only
                w0a = L4(I2b, nyj0, 2 * lane); w0b = L4(I2b, nyj0, 2 * lane + 1);
                w1a = L4(I2b, nyj1, 2 * lane); w1b = L4(I2b, nyj1, 2 * lane + 1);
                w2a = L4(I2b, nyj2, 2 * lane); w2b = L4(I2b, nyj2, 2 * lane + 1);
            }
            w3a = nta; w3b = ntb;
            yj0 = nyj0; yj1 = nyj1; yj2 = nyj2; yj3 = nyj3;
            cpa = cca; cpb = ccb; cca = cna; ccb = cnb; cna = n1a; cnb = n1b;
        }
    }

    // widen to f64, wave butterfly, cross-wave via LDS (single barrier)
    double d0 = a0, d1 = a1, d2 = a2, d3 = a3, d4 = a4;
#pragma unroll
    for (int off = 32; off > 0; off >>= 1) {
        d0 += __shfl_down(d0, off);
        d1 += __shfl_down(d1, off);
        d2 += __shfl_down(d2, off);
        d3 += __shfl_down(d3, off);
        d4 += __shfl_down(d4, off);
    }
    __shared__ double wsum[4][5];
    if (lane == 0) {
        wsum[wv][0] = d0; wsum[wv][1] = d1; wsum[wv][2] = d2;
        wsum[wv][3] = d3; wsum[wv][4] = d4;
    }
    __syncthreads();
    if (tid < 5) {
        double ssum = wsum[0][tid] + wsum[1][tid] + wsum[2][tid] + wsum[3][tid];
        partials[(size_t)tid * COMP_STRIDE + b * NCHUNK + strip] = ssum;
    }
}

__global__ __launch_bounds__(128) void gn_update(const double* __restrict__ partials,
                                                 float* __restrict__ pws,
                                                 float* __restrict__ errws,
                                                 float* __restrict__ out,
                                                 int write_out) {
    __shared__ double Hs[NB][5];
    __shared__ float dpf[NB][2];
    __shared__ float pnew[2 * NB];
    const int tid = threadIdx.x;

    if (tid < NB * 5) {
        int bb = tid & 15, comp = tid >> 4;
        const double* src = partials + (size_t)comp * COMP_STRIDE + bb * NCHUNK;
        double s = 0;
#pragma unroll 8
        for (int ch = 0; ch < NCHUNK; ++ch) s += src[ch];
        Hs[bb][comp] = s;
    }
    __syncthreads();

    if (tid < NB) {
        double H00 = Hs[tid][0], H01 = Hs[tid][1], H11 = Hs[tid][2];
        double b0 = Hs[tid][3], b1 = Hs[tid][4];
        double inv = 1.0 / (H00 * H11 - H01 * H01);
        double dp0 = ( H11 * b0 - H01 * b1) * inv;
        double dp1 = (-H01 * b0 + H00 * b1) * inv;
        dpf[tid][0] = (float)dp0;
        dpf[tid][1] = (float)dp1;
    }
    __syncthreads();

    float err_old = errws[0];
    bool active = err_old > TOLV;

    if (tid < 2 * NB) {
        float pv = pws[tid];
        if (active) pv -= dpf[tid >> 1][tid & 1];
        pnew[tid] = pv;
        pws[tid] = pv;
    }

    float err_new = err_old;
    if (tid == 0) {
        if (active) {
            double n = 0;
            for (int i = 0; i < NB; ++i) {
                n += (double)dpf[i][0] * (double)dpf[i][0];
                n += (double)dpf[i][1] * (double)dpf[i][1];
            }
            err_new = (float)sqrt(n);
            errws[0] = err_new;
        }
    }
    __syncthreads();
    if (write_out) {
        if (tid < 2 * NB) out[tid] = pnew[tid];
        if (tid == 0) out[2 * NB] = err_new;
    }
}

// Barrier-free final warp: same structure, no stats, float4 stores.
__global__ __launch_bounds__(NTHREADS) void gn_final(const float* __restrict__ I1,
                                                     const float* __restrict__ I2,
                                                     const float* __restrict__ pws,
                                                     float* __restrict__ out) {
    const int b = blockIdx.y;
    const int strip = blockIdx.x;
    const int tid = threadIdx.x;
    const int wv = tid >> 6, lane = tid & 63;
    const int c0 = 8 * lane;
    const float tx = pws[2 * b];
    const float ty = pws[2 * b + 1];
    const float* I1b = I1 + (size_t)b * NHW;
    const float* I2b = I2 + (size_t)b * NHW;

    float* DIout = out + 33;
    float* IWout = out + 33 + (size_t)NB * NHW;

    float gx0 = (float)c0 + tx;
    float fx0 = floorf(gx0);
    float dx0 = gx0 - fx0;
    int x00 = (int)fx0;
    const float wx0 = cubicf(dx0 + 1.0f), wx1 = cubicf(dx0);
    const float wx2 = cubicf(dx0 - 1.0f), wx3 = cubicf(dx0 - 2.0f);
    bool fast = true;
#pragma unroll
    for (int j = 1; j < 8; ++j) {
        int xj = (int)floorf((float)(c0 + j) + tx);
        fast = fast && (xj == x00 + j);
    }
    const int base = x00 - 1;
    fast = fast && (base >= -8) && (base + 10 <= NW + 7);
    const int s = base & 3;
    const int wbase = base - s;

    __shared__ float VS[4][NW + 24];
    float* Vw = VS[wv];

    const int ybase = strip * ROWS + wv * RPW;

    int yj0, yj1, yj2, yj3;
    {
        int yy = (int)floorf((float)ybase + ty);
        yj0 = clampy(yy - 1); yj1 = clampy(yy);
        yj2 = clampy(yy + 1); yj3 = clampy(yy + 2);
    }
    float4 w0a = L4(I2b, yj0, 2 * lane), w0b = L4(I2b, yj0, 2 * lane + 1);
    float4 w1a = L4(I2b, yj1, 2 * lane), w1b = L4(I2b, yj1, 2 * lane + 1);
    float4 w2a = L4(I2b, yj2, 2 * lane), w2b = L4(I2b, yj2, 2 * lane + 1);
    float4 w3a = L4(I2b, yj3, 2 * lane), w3b = L4(I2b, yj3, 2 * lane + 1);
    float4 cca = L4(I1b, ybase, 2 * lane), ccb = L4(I1b, ybase, 2 * lane + 1);

#pragma unroll
    for (int r = 0; r < RPW; ++r) {
        const int y = ybase + r;

        float gy = (float)y + ty, fy = floorf(gy), dy = gy - fy;
        const float wy0 = cubicf(dy + 1.0f), wy1 = cubicf(dy);
        const float wy2 = cubicf(dy - 1.0f), wy3 = cubicf(dy - 2.0f);

        int nyj0 = 0, nyj1 = 0, nyj2 = 0, nyj3 = 0;
        bool aligned = true;
        float4 nta, ntb, n1a, n1b;
        if (r + 1 < RPW) {
            int yy2 = (int)floorf((float)(y + 1) + ty);
            nyj0 = clampy(yy2 - 1); nyj1 = clampy(yy2);
            nyj2 = clampy(yy2 + 1); nyj3 = clampy(yy2 + 2);
            aligned = (nyj0 == yj1) && (nyj1 == yj2) && (nyj2 == yj3);
            nta = L4(I2b, nyj3, 2 * lane); ntb = L4(I2b, nyj3, 2 * lane + 1);
            n1a = L4(I1b, y + 1, 2 * lane); n1b = L4(I1b, y + 1, 2 * lane + 1);
        }

        float4 Va, Vb;
        Va.x = wy0 * w0a.x + wy1 * w1a.x + wy2 * w2a.x + wy3 * w3a.x;
        Va.y = wy0 * w0a.y + wy1 * w1a.y + wy2 * w2a.y + wy3 * w3a.y;
        Va.z = wy0 * w0a.z + wy1 * w1a.z + wy2 * w2a.z + wy3 * w3a.z;
        Va.w = wy0 * w0a.w + wy1 * w1a.w + wy2 * w2a.w + wy3 * w3a.w;
        Vb.x = wy0 * w0b.x + wy1 * w1b.x + wy2 * w2b.x + wy3 * w3b.x;
        Vb.y = wy0 * w0b.y + wy1 * w1b.y + wy2 * w2b.y + wy3 * w3b.y;
        Vb.z = wy0 * w0b.z + wy1 * w1b.z + wy2 * w2b.z + wy3 * w3b.z;
        Vb.w = wy0 * w0b.w + wy1 * w1b.w + wy2 * w2b.w + wy3 * w3b.w;
        ((float4*)(Vw + 8))[2 * lane] = Va;
        ((float4*)(Vw + 8))[2 * lane + 1] = Vb;
        if (lane == 0)  { float4 h; h.x = h.y = h.z = h.w = Va.x; ((float4*)Vw)[0] = h; ((float4*)Vw)[1] = h; }
        if (lane == 63) { float4 h; h.x = h.y = h.z = h.w = Vb.w; ((float4*)(Vw + 8 + NW))[0] = h; ((float4*)(Vw + 8 + NW))[1] = h; }

        float Hc[8];
        if (fast) {
            const float4* Wp = (const float4*)(Vw + 8 + wbase);
            float4 W0 = Wp[0], W1 = Wp[1], W2 = Wp[2], W3 = Wp[3];
            float u0, u1, u2, u3, u4, u5, u6, u7, u8, u9, u10;
            switch (s) {
                case 0:  u0=W0.x; u1=W0.y; u2=W0.z; u3=W0.w; u4=W1.x; u5=W1.y; u6=W1.z; u7=W1.w; u8=W2.x; u9=W2.y; u10=W2.z; break;
                case 1:  u0=W0.y; u1=W0.z; u2=W0.w; u3=W1.x; u4=W1.y; u5=W1.z; u6=W1.w; u7=W2.x; u8=W2.y; u9=W2.z; u10=W2.w; break;
                case 2:  u0=W0.z; u1=W0.w; u2=W1.x; u3=W1.y; u4=W1.z; u5=W1.w; u6=W2.x; u7=W2.y; u8=W2.z; u9=W2.w; u10=W3.x; break;
                default: u0=W0.w; u1=W1.x; u2=W1.y; u3=W1.z; u4=W1.w; u5=W2.x; u6=W2.y; u7=W2.z; u8=W2.w; u9=W3.x; u10=W3.y; break;
            }
            Hc[0] = wx0*u0 + wx1*u1 + wx2*u2  + wx3*u3;
            Hc[1] = wx0*u1 + wx1*u2 + wx2*u3  + wx3*u4;
            Hc[2] = wx0*u2 + wx1*u3 + wx2*u4  + wx3*u5;
            Hc[3] = wx0*u3 + wx1*u4 + wx2*u5  + wx3*u6;
            Hc[4] = wx0*u4 + wx1*u5 + wx2*u6  + wx3*u7;
            Hc[5] = wx0*u5 + wx1*u6 + wx2*u7  + wx3*u8;
            Hc[6] = wx0*u6 + wx1*u7 + wx2*u8  + wx3*u9;
            Hc[7] = wx0*u7 + wx1*u8 + wx2*u9  + wx3*u10;
        } else {
#pragma unroll
            for (int j = 0; j < 8; ++j) {
                float g = (float)(c0 + j) + tx;
                float f = floorf(g);
                int x0 = (int)f;
                float d = g - f;
                float v0 = cubicf(d + 1.0f), v1 = cubicf(d);
                float v2 = cubicf(d - 1.0f), v3 = cubicf(d - 2.0f);
                Hc[j] = v0 * Vw[8 + clampx(x0 - 1)] + v1 * Vw[8 + clampx(x0)] +
                        v2 * Vw[8 + clampx(x0 + 1)] + v3 * Vw[8 + clampx(x0 + 2)];
            }
        }

        float cc[8];
        unpack8(cca, ccb, cc);
        float4 dA, dB, wA, wB;
        dA.x = Hc[0] - cc[0]; dA.y = Hc[1] - cc[1]; dA.z = Hc[2] - cc[2]; dA.w = Hc[3] - cc[3];
        dB.x = Hc[4] - cc[4]; dB.y = Hc[5] - cc[5]; dB.z = Hc[6] - cc[6]; dB.w = Hc[7] - cc[7];
        wA.x = Hc[0]; wA.y = Hc[1]; wA.z = Hc[2]; wA.w = Hc[3];
        wB.x = Hc[4]; wB.y = Hc[5]; wB.z = Hc[6]; wB.w = Hc[7];
        size_t o = (size_t)b * NHW + (size_t)y * NW + c0;
        *(float4*)(DIout + o) = dA; *(float4*)(DIout + o + 4) = dB;
        *(float4*)(IWout + o) = wA; *(float4*)(IWout + o + 4) = wB;

        if (r + 1 < RPW) {
            if (aligned) {
                w0a = w1a; w0b = w1b; w1a = w2a; w1b = w2b; w2a = w3a; w2b = w3b;
            } else {
                w0a = L4(I2b, nyj0, 2 * lane); w0b = L4(I2b, nyj0, 2 * lane + 1);
                w1a = L4(I2b, nyj1, 2 * lane); w1b = L4(I2b, nyj1, 2 * lane + 1);
                w2a = L4(I2b, nyj2, 2 * lane); w2b = L4(I2b, nyj2, 2 * lane + 1);
            }
            w3a = nta; w3b = ntb;
            yj0 = nyj0; yj1 = nyj1; yj2 = nyj2; yj3 = nyj3;
            cca = n1a; ccb = n1b;
        }
    }
}

extern "C" void kernel_launch(void* const* d_in, const int* in_sizes, int n_in,
                              void* d_out, int out_size, void* d_ws, size_t ws_size,
                              hipStream_t stream) {
    const float* I1 = (const float*)d_in[0];
    const float* I2 = (const float*)d_in[1];
    const float* p  = (const float*)d_in[2];
    float* out = (float*)d_out;

    double* partials = (double*)d_ws;
    float* pws   = (float*)((char*)d_ws + PWS_OFF);
    float* errws = (float*)((char*)d_ws + ERR_OFF);

    gn_init<<<1, 64, 0, stream>>>(p, pws, errws);

    dim3 grid(NH / ROWS, NB);
    for (int t = 0; t < MAXIT; ++t) {
        gn_reduce<<<grid, NTHREADS, 0, stream>>>(I1, I2, pws, partials);
        gn_update<<<1, 128, 0, stream>>>(partials, pws, errws, out, (t == MAXIT - 1) ? 1 : 0);
    }
    gn_final<<<grid, NTHREADS, 0, stream>>>(I1, I2, pws, out);
}